// Round 2
// baseline (232.550 us; speedup 1.0000x reference)
//
#include <hip/hip_runtime.h>
#include <math.h>

#define DIM 192
#define OD  191          // output domain per axis (191^3)
#define TH  16
#define TW  16
#define NBH 12           // ceil(191/16)
#define CD  12           // d-planes per chunk
#define NCH 16           // ceil(191/12)

typedef float v4 __attribute__((ext_vector_type(4)));

// Fused: diff -> 3x3x3 box mean -> neo-hookean energy -> mean reduction.
// One block = 16x16 (h,w) tile streaming over a chunk of d-planes.
// Fields packed 12-per-point (3x v4) so window sums use ds_read_b128,
// 48B point stride => conflict-free bank pattern for the 4x16 wave footprint.
__global__ __launch_bounds__(256)
void nh_fused_kernel(const float* __restrict__ P, float* __restrict__ out) {
    const int tid = threadIdx.x;
    const int tx  = tid & 15;        // w within tile
    const int ty  = tid >> 4;        // h within tile
    const int w0  = blockIdx.x * TW;
    const int h0  = blockIdx.y * TH;
    const int ds  = blockIdx.z * CD;
    const int de  = min(ds + CD, OD);

    // 9 diff fields packed per point: q0={F0..F3}, q1={F4..F7}, q2={F8,0,0,0}
    // F[dir*3+c]: dir0=H-diff(fx), dir1=D-diff(fy), dir2=W-diff(fz)
    __shared__ v4 sdiff[18][18][3];
    __shared__ float wsum[4];

    const bool valid = (w0 + tx < OD) && (h0 + ty < OD);

    v4 c0[3], c1[3], c2[3];
    #pragma unroll
    for (int q = 0; q < 3; ++q) {
        c0[q] = (v4){0.f, 0.f, 0.f, 0.f};
        c1[q] = (v4){0.f, 0.f, 0.f, 0.f};
        c2[q] = (v4){0.f, 0.f, 0.f, 0.f};
    }

    float acc = 0.f;

    for (int dpl = ds - 1; dpl <= de; ++dpl) {
        __syncthreads();   // protect sdiff from previous iteration's readers

        // Phase 1: build packed diff plane at d' = dpl over halo [h0-1,h0+16]x[w0-1,w0+16]
        for (int l = tid; l < 18 * 18; l += 256) {
            const int hh = l / 18;
            const int ww = l - hh * 18;
            const int hp = h0 - 1 + hh;
            const int wp = w0 - 1 + ww;
            v4 r0 = {0.f, 0.f, 0.f, 0.f};
            v4 r1 = {0.f, 0.f, 0.f, 0.f};
            v4 r2 = {0.f, 0.f, 0.f, 0.f};
            if (dpl >= 0 && dpl < OD && hp >= 0 && hp < OD && wp >= 0 && wp < OD) {
                float dxv[3], dyv[3], dzv[3];
                #pragma unroll
                for (int c = 0; c < 3; ++c) {
                    const size_t base = (((size_t)c * DIM + (size_t)dpl) * DIM + (size_t)hp) * DIM + (size_t)wp;
                    const float b  = P[base];
                    const float pd = P[base + (size_t)DIM * DIM];  // d+1
                    const float ph = P[base + DIM];                // h+1
                    const float pw = P[base + 1];                  // w+1
                    dxv[c] = fabsf(ph - b);   // H-diff (fx)
                    dyv[c] = fabsf(pd - b);   // D-diff (fy)
                    dzv[c] = fabsf(pw - b);   // W-diff (fz)
                }
                r0 = (v4){dxv[0], dxv[1], dxv[2], dyv[0]};
                r1 = (v4){dyv[1], dyv[2], dzv[0], dzv[1]};
                r2 = (v4){dzv[2], 0.f, 0.f, 0.f};
            }
            sdiff[hh][ww][0] = r0;
            sdiff[hh][ww][1] = r1;
            sdiff[hh][ww][2] = r2;
        }
        __syncthreads();

        // Phase 2: 3x3 2D window sums at this plane (vectorized); rotate ring
        #pragma unroll
        for (int q = 0; q < 3; ++q) { c0[q] = c1[q]; c1[q] = c2[q]; }
        {
            v4 s0 = {0.f,0.f,0.f,0.f}, s1 = {0.f,0.f,0.f,0.f}, s2 = {0.f,0.f,0.f,0.f};
            #pragma unroll
            for (int j = 0; j < 3; ++j) {
                #pragma unroll
                for (int k = 0; k < 3; ++k) {
                    s0 += sdiff[ty + j][tx + k][0];
                    s1 += sdiff[ty + j][tx + k][1];
                    s2 += sdiff[ty + j][tx + k][2];
                }
            }
            c2[0] = s0; c2[1] = s1; c2[2] = s2;
        }

        // Phase 3: emit output voxel at d = dpl - 1 (needs planes d-1,d,d+1)
        const int d = dpl - 1;
        if (valid && d >= ds && d < de) {
            const float inv27 = 1.f / 27.f;
            v4 F0 = (c0[0] + c1[0] + c2[0]) * inv27;
            v4 F1 = (c0[1] + c1[1] + c2[1]) * inv27;
            v4 F2 = (c0[2] + c1[2] + c2[2]) * inv27;
            const float dydx = F0.x, dxdx = F0.y, dzdx = F0.z, dydy = F0.w;
            const float dxdy = F1.x, dzdy = F1.y, dydz = F1.z, dxdz = F1.w;
            const float dzdz = F2.x;
            const float a = dxdx + 1.f, e = dydy + 1.f, iN = dzdz + 1.f;
            const float J = a * (e * iN - dydz * dzdy)
                          - dxdy * (dydx * iN - dydz * dzdx)
                          + dxdz * (dydx * dzdy - e * dzdx);
            const float Tr = a * a + dxdy * dxdy + dxdz * dxdz
                           + dydx * dydx + e * e + dydz * dydz
                           + dzdx * dzdx + dzdy * dzdy + iN * iN;
            const float stretch = Tr * expf(1.f - J) - 3.f;
            const float vol = (J - 1.f) * (J - 1.f);
            // mu=1,lam=5 -> U = (1/12)*stretch + (15/31)*vol  (matches round-1 verified consts)
            acc += 0.0833333358f * stretch + 0.4838709677f * vol;
        }
    }

    // mean scaling (191^3)
    acc *= (1.f / 6967871.f);

    // wave reduce (64 lanes), then block reduce, one atomic per block
    #pragma unroll
    for (int off = 32; off > 0; off >>= 1) acc += __shfl_down(acc, off, 64);
    if ((tid & 63) == 0) wsum[tid >> 6] = acc;
    __syncthreads();
    if (tid == 0) {
        atomicAdd(out, wsum[0] + wsum[1] + wsum[2] + wsum[3]);
    }
}

extern "C" void kernel_launch(void* const* d_in, const int* in_sizes, int n_in,
                              void* d_out, int out_size, void* d_ws, size_t ws_size,
                              hipStream_t stream) {
    const float* y_pred = (const float*)d_in[0];
    float* out = (float*)d_out;

    // d_out is poisoned 0xAA before every timed launch — zero it (graph-capturable).
    hipMemsetAsync(out, 0, sizeof(float), stream);

    dim3 grid(NBH, NBH, NCH);
    nh_fused_kernel<<<grid, 256, 0, stream>>>(y_pred, out);
}

// Round 3
// 189.934 us; speedup vs baseline: 1.2244x; 1.2244x over previous
//
#include <hip/hip_runtime.h>
#include <math.h>

#define DIM 192
#define OD  191          // output domain per axis (191^3 outputs)
#define PLANE 36864      // 192*192
#define VOL  7077888     // 192^3
#define TH  16
#define TW  16
#define NBH 12           // ceil(191/16)
#define CD  14           // d-planes per chunk
#define NCH 14           // 14*14=196 >= 191

typedef float f4 __attribute__((ext_vector_type(4)));
typedef _Float16 h8 __attribute__((ext_vector_type(8)));
typedef _Float16 h2 __attribute__((ext_vector_type(2)));

// Fused: diff -> 3x3x3 box mean -> neo-hookean energy -> mean reduction.
// Raw planes staged in a 2-deep LDS ring (each global plane read ONCE);
// 9 diff fields packed as f16 (half8+half2 = 20B/point) so window sums
// are ds_read_b128 + v_pk_add_f16.
__global__ __launch_bounds__(256, 8)
void nh_fused_kernel(const float* __restrict__ P, float* __restrict__ out) {
    const int tid = threadIdx.x;
    const int tx  = tid & 15;        // w within tile
    const int ty  = tid >> 4;        // h within tile
    const int w0  = blockIdx.x * TW;
    const int h0  = blockIdx.y * TH;
    const int ds  = blockIdx.z * CD;
    const int de  = min(ds + CD, OD);

    __shared__ f4 sraw[2][19][20];   // raw y_pred, .xyz = channels 0..2; 19x19 halo, w-padded
    __shared__ h8 sA[18][19];        // fields {Hd0,Hd1,Hd2,Dd0,Dd1,Dd2,Wd0,Wd1}
    __shared__ h2 sB[18][19];        // field  {Wd2, pad}
    __shared__ float wsum[4];

    const bool valid = (w0 + tx < OD) && (h0 + ty < OD);

    h8 a0 = (h8)0, a1 = (h8)0, a2 = (h8)0;
    h2 b0 = (h2)0, b1 = (h2)0, b2 = (h2)0;
    float acc = 0.f;

    for (int t = ds - 1; t <= de + 1; ++t) {
        const int cb = t & 1, pb = cb ^ 1;

        // (a) stage raw plane t into LDS ring (3 channels -> one float4 store)
        if (t >= 0 && t < DIM) {
            for (int l = tid; l < 19 * 19; l += 256) {
                const int hh = l / 19;
                const int ww = l - hh * 19;
                const int hp = h0 - 1 + hh;
                const int wp = w0 - 1 + ww;
                if (hp >= 0 && hp < DIM && wp >= 0 && wp < DIM) {
                    const size_t base = ((size_t)t * DIM + (size_t)hp) * DIM + (size_t)wp;
                    f4 r;
                    r.x = P[base];
                    r.y = P[base + VOL];
                    r.z = P[base + 2 * VOL];
                    r.w = 0.f;
                    sraw[cb][hh][ww] = r;
                }
            }
        }
        __syncthreads();

        // (c) build packed f16 diff plane p = t-1 (prev buffer = plane p, cur = p+1)
        const int p = t - 1;
        const bool pplane = (p >= 0) && (p < OD) && (t >= ds);  // t>=ds: prev buffer is loaded
        for (int l = tid; l < 18 * 18; l += 256) {
            const int hh = l / 18;
            const int ww = l - hh * 18;
            const int hp = h0 - 1 + hh;
            const int wp = w0 - 1 + ww;
            h8 va = (h8)0;
            h2 vb = (h2)0;
            if (pplane && hp >= 0 && hp < OD && wp >= 0 && wp < OD) {
                const f4 c  = sraw[pb][hh][ww];        // (p, hp, wp)
                const f4 ch = sraw[pb][hh + 1][ww];    // (p, hp+1, wp)
                const f4 cw = sraw[pb][hh][ww + 1];    // (p, hp, wp+1)
                const f4 cd = sraw[cb][hh][ww];        // (p+1, hp, wp)
                const float hx = fabsf(ch.x - c.x), hy = fabsf(ch.y - c.y), hz = fabsf(ch.z - c.z);
                const float dx_ = fabsf(cd.x - c.x), dy_ = fabsf(cd.y - c.y), dz_ = fabsf(cd.z - c.z);
                const float wx = fabsf(cw.x - c.x), wy = fabsf(cw.y - c.y), wz = fabsf(cw.z - c.z);
                va = (h8){(_Float16)hx, (_Float16)hy, (_Float16)hz,
                          (_Float16)dx_, (_Float16)dy_, (_Float16)dz_,
                          (_Float16)wx, (_Float16)wy};
                vb = (h2){(_Float16)wz, (_Float16)0.f};
            }
            sA[hh][ww] = va;
            sB[hh][ww] = vb;
        }
        __syncthreads();

        // (e) 3x3 window sums (packed f16); rotate ring; emit d = t-2
        a0 = a1; a1 = a2; b0 = b1; b1 = b2;
        {
            h8 sa = (h8)0;
            h2 sb = (h2)0;
            #pragma unroll
            for (int j = 0; j < 3; ++j) {
                #pragma unroll
                for (int k = 0; k < 3; ++k) {
                    sa += sA[ty + j][tx + k];
                    sb += sB[ty + j][tx + k];
                }
            }
            a2 = sa; b2 = sb;
        }

        const int d = t - 2;
        if (valid && d >= ds && d < de) {
            const h8 FA = a0 + a1 + a2;
            const h2 FB = b0 + b1 + b2;
            const float inv27 = 1.f / 27.f;
            const float dydx = (float)FA[0] * inv27, dxdx = (float)FA[1] * inv27, dzdx = (float)FA[2] * inv27;
            const float dydy = (float)FA[3] * inv27, dxdy = (float)FA[4] * inv27, dzdy = (float)FA[5] * inv27;
            const float dydz = (float)FA[6] * inv27, dxdz = (float)FA[7] * inv27, dzdz = (float)FB[0] * inv27;
            const float a = dxdx + 1.f, e = dydy + 1.f, iN = dzdz + 1.f;
            const float J = a * (e * iN - dydz * dzdy)
                          - dxdy * (dydx * iN - dydz * dzdx)
                          + dxdz * (dydx * dzdy - e * dzdx);
            const float Tr = a * a + dxdy * dxdy + dxdz * dxdz
                           + dydx * dydx + e * e + dydz * dydz
                           + dzdx * dzdx + dzdy * dzdy + iN * iN;
            const float stretch = Tr * expf(1.f - J) - 3.f;
            const float vol = (J - 1.f) * (J - 1.f);
            // mu=1,lam=5 -> U = (1/12)*stretch + (15/31)*vol (verified exact in round 1)
            acc += 0.0833333358f * stretch + 0.4838709677f * vol;
        }
    }

    // mean scaling (191^3)
    acc *= (1.f / 6967871.f);

    // wave reduce (64 lanes), then block reduce, one atomic per block
    #pragma unroll
    for (int off = 32; off > 0; off >>= 1) acc += __shfl_down(acc, off, 64);
    if ((tid & 63) == 0) wsum[tid >> 6] = acc;
    __syncthreads();
    if (tid == 0) {
        atomicAdd(out, wsum[0] + wsum[1] + wsum[2] + wsum[3]);
    }
}

extern "C" void kernel_launch(void* const* d_in, const int* in_sizes, int n_in,
                              void* d_out, int out_size, void* d_ws, size_t ws_size,
                              hipStream_t stream) {
    const float* y_pred = (const float*)d_in[0];
    float* out = (float*)d_out;

    // d_out is poisoned 0xAA before every timed launch — zero it (graph-capturable).
    hipMemsetAsync(out, 0, sizeof(float), stream);

    dim3 grid(NBH, NBH, NCH);
    nh_fused_kernel<<<grid, 256, 0, stream>>>(y_pred, out);
}